// Round 18
// baseline (137.424 us; speedup 1.0000x reference)
//
#include <hip/hip_runtime.h>
#include <hip/hip_bf16.h>

typedef __attribute__((ext_vector_type(8))) short bf16x8;
typedef __attribute__((ext_vector_type(4))) float f32x4;
typedef __attribute__((ext_vector_type(16))) float f32x16;
typedef __attribute__((ext_vector_type(4))) unsigned int u32x4;
typedef __attribute__((ext_vector_type(2))) unsigned int u32x2;

#define Bn 8
#define Tn 2048
#define Kn 64
#define Hn 8
#define KSn 5
#define CHn 512
#define TPADn 2052  /* 4 zero rows + 2048 */

__device__ __forceinline__ unsigned short f2bf(float f) {
    unsigned int x = __builtin_bit_cast(unsigned int, f);
    unsigned int r = (x + 0x7fffu + ((x >> 16) & 1u)) >> 16;
    return (unsigned short)r;
}

__device__ __forceinline__ unsigned int cvt_pk_bf16(float lo, float hi) {
    unsigned int r;
    asm("v_cvt_pk_bf16_f32 %0, %1, %2" : "=v"(r) : "v"(lo), "v"(hi));
    return r;
}

__device__ __forceinline__ float fast_exp2(float x) {
#if __has_builtin(__builtin_amdgcn_exp2f)
    return __builtin_amdgcn_exp2f(x);
#else
    float r;
    asm("v_exp_f32 %0, %1" : "=v"(r) : "v"(x));
    return r;
#endif
}

// cross-half (lane ^ 32) merges: validated shfl_xor path (rounds 1-4,7-16).
__device__ __forceinline__ float xhalf_max(float v) {
    return fmaxf(v, __shfl_xor(v, 32));
}
__device__ __forceinline__ float xhalf_add(float v) {
    return v + __shfl_xor(v, 32);
}

// distinct-operand two-register permute (validated in P-repack since round 1)
__device__ __forceinline__ u32x2 pl32swap(unsigned int x, unsigned int y) {
#if __has_builtin(__builtin_amdgcn_permlane32_swap)
    return __builtin_amdgcn_permlane32_swap(x, y, false, false);
#else
    unsigned int xs = (unsigned int)__shfl_xor((int)x, 32);
    unsigned int ys = (unsigned int)__shfl_xor((int)y, 32);
    int hi = (threadIdx.x & 63) >> 5;
    u32x2 r;
    r[0] = hi ? ys : x;   // {x.lo | y.lo}
    r[1] = hi ? y : xs;   // {x.hi | y.hi}
    return r;
#endif
}

__device__ __forceinline__ void gload_lds16(const void* g, void* l) {
    __builtin_amdgcn_global_load_lds(
        (const __attribute__((address_space(1))) void*)g,
        (__attribute__((address_space(3))) void*)l, 16, 0, 0);
}

// ---------------- prep: conversions + padded x + weight reformat + scale folding ----
__global__ void prep_kernel(const float* __restrict__ x,
                            const float* __restrict__ wq, const float* __restrict__ bq,
                            const float* __restrict__ wk, const float* __restrict__ bk,
                            const float* __restrict__ wv,
                            const float* __restrict__ wu,
                            unsigned short* __restrict__ x_pad,
                            unsigned short* __restrict__ w2q, unsigned short* __restrict__ w2k,
                            unsigned short* __restrict__ w2v,
                            unsigned short* __restrict__ wu_b,
                            float* __restrict__ bqs, float* __restrict__ bks)
{
    // 64^-0.25 * sqrt(log2(e)): scores come out pre-multiplied by log2(e)
    const float inv_scale = 0.424660900144f;
    const int N0 = Bn*TPADn*Kn;
    const int N1 = KSn*CHn*Kn;
    const int total = N0 + 3*N1 + CHn*Kn + 2*CHn;
    for (int i = blockIdx.x*blockDim.x + threadIdx.x; i < total; i += gridDim.x*blockDim.x) {
        if (i < N0) {
            int b = i / (TPADn*Kn);
            int rem = i - b*(TPADn*Kn);
            int p = rem >> 6, ic = rem & 63;
            x_pad[i] = (p < 4) ? (unsigned short)0
                               : f2bf(x[((size_t)b*Tn + (p - 4))*Kn + ic]);
            continue;
        }
        int r = i - N0;
        if (r < 3*N1) {
            int conv = r / N1; int rr = r - conv*N1;
            int j = rr / (CHn*Kn); int rc = rr - j*(CHn*Kn);
            int c = rc >> 6; int ic = rc & 63;
            const float* w = (conv==0) ? wq : ((conv==1) ? wk : wv);
            float s = (conv==2) ? 1.0f : inv_scale;
            unsigned short* dst = (conv==0) ? w2q : ((conv==1) ? w2k : w2v);
            dst[rr] = f2bf(w[(c*Kn + ic)*KSn + j] * s);
            continue;
        }
        r -= 3*N1;
        if (r < CHn*Kn) { wu_b[r] = f2bf(wu[r]); continue; }
        r -= CHn*Kn;
        if (r < CHn) { bqs[r] = bq[r]*inv_scale; continue; }
        r -= CHn;
        bks[r] = bk[r]*inv_scale;
    }
}

// ---------------- conv v4: register weights, LDS-staged x (dbuf), 8 t-tiles/block ---
__global__ __launch_bounds__(256) void conv_v4(
    const unsigned short* __restrict__ x_pad,
    const unsigned short* __restrict__ w2q, const unsigned short* __restrict__ w2k,
    const unsigned short* __restrict__ w2v,
    const float* __restrict__ bqs, const float* __restrict__ bks,
    unsigned short* __restrict__ q_s, unsigned short* __restrict__ k_s,
    unsigned short* __restrict__ v_t)
{
    __shared__ __align__(16) unsigned short xs[2][72*64];
    __shared__ __align__(16) unsigned short ts[64*64];
    const int tg = blockIdx.x;
    const int c0 = blockIdx.y * 64;
    const int zz = blockIdx.z;
    const int conv = zz >> 3, b = zz & 7;
    const unsigned short* w2 = (conv==0) ? w2q : ((conv==1) ? w2k : w2v);
    const float* bias = (conv==0) ? bqs : ((conv==1) ? bks : nullptr);
    unsigned short* outp = (conv==0) ? q_s : ((conv==1) ? k_s : v_t);
    const int tid = threadIdx.x;
    const int wid = tid >> 6, l = tid & 63;
    const int lr = l & 15, lh = l >> 4;
    const int wt = wid & 1, wc = wid >> 1;

    bf16x8 wf[5][2][2];
    #pragma unroll
    for (int j = 0; j < 5; ++j)
        #pragma unroll
        for (int kk = 0; kk < 2; ++kk)
            #pragma unroll
            for (int n2 = 0; n2 < 2; ++n2)
                wf[j][kk][n2] = *(const bf16x8*)
                    &w2[(j*CHn + c0 + wc*32 + n2*16 + lr)*Kn + kk*32 + lh*8];
    float bv0 = bias ? bias[c0 + wc*32 + lr]      : 0.0f;
    float bv1 = bias ? bias[c0 + wc*32 + 16 + lr] : 0.0f;

    const int swz_row = l >> 3;
    const int src_inrow = ((l & 7) << 4) ^ (swz_row << 4);

    int buf = 0;
    {
        const char* base = (const char*)(x_pad + (size_t)b*TPADn*Kn);
        int p0 = tg*512;
        for (int i = wid; i < 9; i += 4) {
            const char* src = base + (size_t)(p0 + i*8 + swz_row)*128 + src_inrow;
            gload_lds16(src, (char*)&xs[0][0] + i*1024);
        }
    }
    __syncthreads();

    for (int tt = 0; tt < 8; ++tt) {
        const int t0 = (tg*8 + tt)*64;
        if (tt < 7) {
            const char* base = (const char*)(x_pad + (size_t)b*TPADn*Kn);
            int p0 = t0 + 64;
            for (int i = wid; i < 9; i += 4) {
                const char* src = base + (size_t)(p0 + i*8 + swz_row)*128 + src_inrow;
                gload_lds16(src, (char*)&xs[buf^1][0] + i*1024);
            }
        }
        const char* xb = (const char*)&xs[buf][0];
        f32x4 acc[2][2] = {};
        #pragma unroll
        for (int j = 0; j < 5; ++j)
            #pragma unroll
            for (int kk = 0; kk < 2; ++kk) {
                #pragma unroll
                for (int m = 0; m < 2; ++m) {
                    int row = wt*32 + m*16 + lr + j;
                    bf16x8 a = *(const bf16x8*)
                        (xb + row*128 + ((kk*64 + lh*16) ^ ((row & 7) << 4)));
                    acc[m][0] = __builtin_amdgcn_mfma_f32_16x16x32_bf16(a, wf[j][kk][0], acc[m][0], 0, 0, 0);
                    acc[m][1] = __builtin_amdgcn_mfma_f32_16x16x32_bf16(a, wf[j][kk][1], acc[m][1], 0, 0, 0);
                }
            }
        __syncthreads();
        #pragma unroll
        for (int m = 0; m < 2; ++m)
            #pragma unroll
            for (int n2 = 0; n2 < 2; ++n2) {
                float bv = n2 ? bv1 : bv0;
                int cl = wc*32 + n2*16 + lr;
                #pragma unroll
                for (int reg = 0; reg < 4; ++reg) {
                    int tl = wt*32 + m*16 + lh*4 + reg;
                    ts[(tl*64 + cl) ^ ((tl & 7) << 3)] = f2bf(acc[m][n2][reg] + bv);
                }
            }
        __syncthreads();
        if (conv < 2) {
            #pragma unroll
            for (int it = 0; it < 2; ++it) {
                int idx = tid + it*256;
                int tl = idx >> 3, hl = idx & 7;
                unsigned short tmp[8];
                #pragma unroll
                for (int dl = 0; dl < 8; ++dl)
                    tmp[dl] = ts[(tl*64 + hl + 8*dl) ^ ((tl & 7) << 3)];
                size_t el = ((size_t)(b*Hn + hl)*Tn + t0 + tl)*Kn + (c0 >> 3);
                *(u32x4*)&outp[el] = *(u32x4*)tmp;
            }
        } else {
            #pragma unroll
            for (int it = 0; it < 2; ++it) {
                int idx = tid + it*256;
                int tc = idx >> 6, cl2 = idx & 63;
                int hl = cl2 & 7, dl = cl2 >> 3;
                unsigned short tmp[8];
                #pragma unroll
                for (int i2 = 0; i2 < 8; ++i2)
                    tmp[i2] = ts[((tc*8 + i2)*64 + cl2) ^ (((tc*8 + i2) & 7) << 3)];
                size_t el = ((size_t)(b*Hn + hl)*Kn + (c0 >> 3) + dl)*Tn + t0 + tc*8;
                *(u32x4*)&outp[el] = *(u32x4*)tmp;
            }
        }
        buf ^= 1;
    }
}

// ---- attn v14: block-cooperative PAIR staging (KVBLK=64), joint softmax ------------
// r16's cooperative structure + r15's pair amortization; LDS 32KB -> occupancy kept.
// Tiles/block = 4j+4 (even) -> pairs always complete, no tail.
__global__ __launch_bounds__(256, 4) void attn_kernel(
    const unsigned short* __restrict__ q_s, const unsigned short* __restrict__ k_s,
    const unsigned short* __restrict__ v_t, unsigned short* __restrict__ attn2)
{
    __shared__ __align__(16) unsigned char lds_raw[32768];  // K pair-dbuf 16KB + V 16KB
    const int tid = threadIdx.x;
    const int wid = tid >> 6, l = tid & 63;
    const int lq = l & 31, hi = l >> 5;
    const int bx = blockIdx.x;                   // 1024 blocks
    const int bh = (bx & 7)*8 + ((bx >> 3) & 7); // 8 heads per XCD (K+V fits L2)
    const int s4g = (bx >> 6) & 3, g = bx >> 8;
    const int j = (g == 0) ? s4g : (g == 1) ? 15 - s4g : (g == 2) ? 7 - s4g : 8 + s4g;
    const int cw = 4*j + wid;      // this wave's chunk
    const int npairs = 2*j + 2;    // tiles 0..4j+3 walked as pairs
    const int qw = cw * 32;
    const unsigned short* qp = q_s + (size_t)bh*Tn*Kn;
    const char* kpc = (const char*)(k_s + (size_t)bh*Tn*Kn);
    const char* vpc = (const char*)(v_t + (size_t)bh*Kn*Tn);
    unsigned short* op = attn2 + (size_t)bh*Tn*Kn;
    const int qg = qw + lq;

    // block-cooperative stage: thread -> 16B of each of 2 K tiles + 2 V tiles
    const int krow = wid*8 + (l >> 3);
    const char* kSrc0 = kpc + krow*128 + (((l & 7) ^ (krow & 7)) << 4);
    const char* vSrc0 = vpc + (size_t)krow*8192 + ((l >> 2) & 1)*4096
                      + ((((l & 3) ^ (krow & 3))) << 4);
    const int dstOff = wid*1024;   // wave-uniform LDS dst (HW adds lane*16)
    auto stage = [&](int pp, int t) {
        gload_lds16(kSrc0 + (size_t)t*4096,       lds_raw + pp*8192 + dstOff);
        gload_lds16(kSrc0 + (size_t)(t+1)*4096,   lds_raw + pp*8192 + 4096 + dstOff);
        gload_lds16(vSrc0 + (size_t)t*64,         lds_raw + 16384 + pp*8192 + dstOff);
        gload_lds16(vSrc0 + (size_t)(t+1)*64,     lds_raw + 16384 + pp*8192 + 4096 + dstOff);
    };

    bf16x8 qf[4];
    #pragma unroll
    for (int m = 0; m < 4; ++m)
        qf[m] = *(const bf16x8*)&qp[(qw + lq)*Kn + m*16 + hi*8];

    f32x16 o0 = (f32x16)(0.0f), o1 = (f32x16)(0.0f);
    float m_run = -1e30f, l_run = 0.f;   // l_run per-lane-HALF (merged at end)

    const int kReadBase = lq*128;
    const int kReadSwz  = (lq & 7) << 4;
    const int vReadBase = (lq >> 1)*128 + (lq & 1)*64;
    const int vSwz = (lq >> 1) & 3;

    stage(0, 0);
    __syncthreads();
    int p = 0;
    for (int pi = 0; pi < npairs; ++pi) {
        const int t = 2*pi;
        if (pi + 1 < npairs) stage(p ^ 1, t + 2);
        if (t <= cw) {
            const char* sK0 = (const char*)lds_raw + p*8192;
            const char* sK1 = sK0 + 4096;
            const char* sV0 = (const char*)lds_raw + 16384 + p*8192;
            const char* sV1 = sV0 + 4096;
            bf16x8 k0[4], k1[4], v0[2][2], v1[2][2];
            #pragma unroll
            for (int m = 0; m < 4; ++m) {
                k0[m] = *(const bf16x8*)(sK0 + kReadBase + ((m*32 + hi*16) ^ kReadSwz));
                k1[m] = *(const bf16x8*)(sK1 + kReadBase + ((m*32 + hi*16) ^ kReadSwz));
            }
            #pragma unroll
            for (int dn = 0; dn < 2; ++dn)
                #pragma unroll
                for (int ks = 0; ks < 2; ++ks) {
                    v0[dn][ks] = *(const bf16x8*)
                        (sV0 + dn*2048 + vReadBase + (((ks*2 + hi) ^ vSwz) << 4));
                    v1[dn][ks] = *(const bf16x8*)
                        (sV1 + dn*2048 + vReadBase + (((ks*2 + hi) ^ vSwz) << 4));
                }
            // QK for both sub-tiles
            f32x16 s = (f32x16)(0.0f), s2 = (f32x16)(0.0f);
            #pragma unroll
            for (int m = 0; m < 4; ++m)
                s  = __builtin_amdgcn_mfma_f32_32x32x16_bf16(k0[m], qf[m], s, 0, 0, 0);
            #pragma unroll
            for (int m = 0; m < 4; ++m)
                s2 = __builtin_amdgcn_mfma_f32_32x32x16_bf16(k1[m], qf[m], s2, 0, 0, 0);
            // masks: sub0 causal iff t==cw; sub1 dead iff t+1>cw, causal iff t+1==cw
            if (t == cw) {
                const int s0g = t*32;
                #pragma unroll
                for (int r = 0; r < 16; ++r) {
                    int sg = s0g + (r & 3) + 8*(r >> 2) + 4*hi;
                    if (sg > qg) s[r] = -1e30f;
                }
            }
            if (t + 1 > cw) {
                #pragma unroll
                for (int r = 0; r < 16; ++r) s2[r] = -1e30f;
            } else if (t + 1 == cw) {
                const int s0g = (t + 1)*32;
                #pragma unroll
                for (int r = 0; r < 16; ++r) {
                    int sg = s0g + (r & 3) + 8*(r >> 2) + 4*hi;
                    if (sg > qg) s2[r] = -1e30f;
                }
            }
            // joint softmax over 32 values
            float a8[8];
            #pragma unroll
            for (int r = 0; r < 8; ++r)
                a8[r] = fmaxf(fmaxf(s[r], s[r + 8]), fmaxf(s2[r], s2[r + 8]));
            float a4_0 = fmaxf(a8[0], a8[4]), a4_1 = fmaxf(a8[1], a8[5]);
            float a4_2 = fmaxf(a8[2], a8[6]), a4_3 = fmaxf(a8[3], a8[7]);
            float mt = fmaxf(fmaxf(a4_0, a4_1), fmaxf(a4_2, a4_3));
            mt = xhalf_max(mt);
            if (!__all(mt <= m_run + 8.0f)) {   // defer-max (log2 domain, THR=8)
                float mn = fmaxf(m_run, mt);
                float alpha = fast_exp2(m_run - mn);
                m_run = mn;
                l_run *= alpha;
                #pragma unroll
                for (int r = 0; r < 16; ++r) { o0[r] *= alpha; o1[r] *= alpha; }
            }
            float ps[4] = {0.f, 0.f, 0.f, 0.f};
            #pragma unroll
            for (int r = 0; r < 16; ++r) {
                float pv = fast_exp2(s[r] - m_run);
                s[r] = pv; ps[r & 3] += pv;
                float pv2 = fast_exp2(s2[r] - m_run);
                s2[r] = pv2; ps[r & 3] += pv2;
            }
            l_run += (ps[0] + ps[1]) + (ps[2] + ps[3]);
            unsigned int W[8], W2[8];
            #pragma unroll
            for (int rp = 0; rp < 8; ++rp) {
                W[rp]  = cvt_pk_bf16(s[2*rp],  s[2*rp + 1]);
                W2[rp] = cvt_pk_bf16(s2[2*rp], s2[2*rp + 1]);
            }
            u32x4 bw[2], bw2[2];
            #pragma unroll
            for (int m = 0; m < 2; ++m)
                #pragma unroll
                for (int jp = 0; jp < 2; ++jp) {
                    u32x2 sw = pl32swap(W[jp + 4*m], W[jp + 4*m + 2]);
                    bw[m][jp]     = sw[0];
                    bw[m][jp + 2] = sw[1];
                    u32x2 sw2 = pl32swap(W2[jp + 4*m], W2[jp + 4*m + 2]);
                    bw2[m][jp]     = sw2[0];
                    bw2[m][jp + 2] = sw2[1];
                }
            o0 = __builtin_amdgcn_mfma_f32_32x32x16_bf16(v0[0][0], __builtin_bit_cast(bf16x8, bw[0]),  o0, 0, 0, 0);
            o0 = __builtin_amdgcn_mfma_f32_32x32x16_bf16(v0[0][1], __builtin_bit_cast(bf16x8, bw[1]),  o0, 0, 0, 0);
            o0 = __builtin_amdgcn_mfma_f32_32x32x16_bf16(v1[0][0], __builtin_bit_cast(bf16x8, bw2[0]), o0, 0, 0, 0);
            o0 = __builtin_amdgcn_mfma_f32_32x32x16_bf16(v1[0][1], __builtin_bit_cast(bf16x8, bw2[1]), o0, 0, 0, 0);
            o1 = __builtin_amdgcn_mfma_f32_32x32x16_bf16(v0[1][0], __builtin_bit_cast(bf16x8, bw[0]),  o1, 0, 0, 0);
            o1 = __builtin_amdgcn_mfma_f32_32x32x16_bf16(v0[1][1], __builtin_bit_cast(bf16x8, bw[1]),  o1, 0, 0, 0);
            o1 = __builtin_amdgcn_mfma_f32_32x32x16_bf16(v1[1][0], __builtin_bit_cast(bf16x8, bw2[0]), o1, 0, 0, 0);
            o1 = __builtin_amdgcn_mfma_f32_32x32x16_bf16(v1[1][1], __builtin_bit_cast(bf16x8, bw2[1]), o1, 0, 0, 0);
        }
        __syncthreads();   // buf[p] reads done; buf[p^1] stage landed
        p ^= 1;
    }

    // epilogue: merge l across halves once, normalize, per-wave LDS transpose
    float l_full = xhalf_add(l_run);
    char* myLds = (char*)lds_raw + wid*4096;   // stage buffers dead after final barrier
    float inv_l = 1.0f / l_full;
    #pragma unroll
    for (int e = 0; e < 16; e += 2) {
        int dd = (e & 3) + 8*(e >> 2) + 4*hi;
        unsigned int wv0 = cvt_pk_bf16(o0[e]*inv_l, o0[e+1]*inv_l);
        *(unsigned int*)(myLds + ((lq*128 + dd*2)      ^ ((lq & 7) << 4))) = wv0;
        unsigned int wv1 = cvt_pk_bf16(o1[e]*inv_l, o1[e+1]*inv_l);
        *(unsigned int*)(myLds + ((lq*128 + 64 + dd*2) ^ ((lq & 7) << 4))) = wv1;
    }
    int q2 = l >> 1, hf = l & 1;
    #pragma unroll
    for (int o4 = 0; o4 < 4; ++o4) {
        u32x4 vr2 = *(u32x4*)(myLds + ((q2*128 + hf*64 + o4*16) ^ ((q2 & 7) << 4)));
        *(u32x4*)&op[(qw + q2)*Kn + hf*32 + o4*8] = vr2;
    }
}

// ---------------- output projection: 16 rows/block, 4-way K-split + LDS reduce ------
__global__ __launch_bounds__(256) void proj_kernel(
    const unsigned short* __restrict__ attn, const unsigned short* __restrict__ wu_b,
    const float* __restrict__ bu, float* __restrict__ outp)
{
    __shared__ float red[4*16*66];
    const int r0 = blockIdx.x * 16;
    const int tid = threadIdx.x;
    const int w = tid >> 6, l = tid & 63;
    const int lr = l & 15, lh = l >> 4;
    f32x4 acc[4] = {};
    const int r = r0 + lr;
    const int bb = r >> 11, tt = r & 2047;
    #pragma unroll
    for (int ki = 0; ki < 4; ++ki) {
        int kk = w*4 + ki;
        int ch = kk*32 + lh*8;
        int hh = ch >> 6, dd = ch & 63;
        bf16x8 a = *(const bf16x8*)&attn[(size_t)((bb*Hn + hh)*Tn + tt)*Kn + dd];
        #pragma unroll
        for (int n = 0; n < 4; ++n) {
            bf16x8 bf = *(const bf16x8*)&wu_b[(n*16 + lr)*CHn + ch];
            acc[n] = __builtin_amdgcn_mfma_f32_16x16x32_bf16(a, bf, acc[n], 0, 0, 0);
        }
    }
    #pragma unroll
    for (int n = 0; n < 4; ++n)
        #pragma unroll
        for (int reg = 0; reg < 4; ++reg)
            red[w*1056 + (lh*4 + reg)*66 + n*16 + lr] = acc[n][reg];
    __syncthreads();
    #pragma unroll
    for (int it = 0; it < 4; ++it) {
        int idx = tid + it*256;
        int rl = idx >> 6, ko = idx & 63;
        float s = red[rl*66 + ko] + red[1056 + rl*66 + ko]
                + red[2112 + rl*66 + ko] + red[3168 + rl*66 + ko] + bu[ko];
        outp[(size_t)(r0 + rl)*Kn + ko] = s;
    }
}

extern "C" void kernel_launch(void* const* d_in, const int* in_sizes, int n_in,
                              void* d_out, int out_size, void* d_ws, size_t ws_size,
                              hipStream_t stream)
{
    const float* x  = (const float*)d_in[0];
    const float* wq = (const float*)d_in[1];
    const float* bq = (const float*)d_in[2];
    const float* wk = (const float*)d_in[3];
    const float* bk = (const float*)d_in[4];
    const float* wv = (const float*)d_in[5];
    const float* wu = (const float*)d_in[6];
    const float* bu = (const float*)d_in[7];
    float* outp = (float*)d_out;

    char* ws = (char*)d_ws;
    size_t off = 0;
    auto alloc = [&](size_t bytes) {
        char* p = ws + off;
        off = (off + bytes + 255) & ~(size_t)255;
        return p;
    };
    unsigned short* x_pad = (unsigned short*)alloc((size_t)Bn*TPADn*Kn*2);
    unsigned short* w2q  = (unsigned short*)alloc((size_t)KSn*CHn*Kn*2);
    unsigned short* w2k  = (unsigned short*)alloc((size_t)KSn*CHn*Kn*2);
    unsigned short* w2v  = (unsigned short*)alloc((size_t)KSn*CHn*Kn*2);
    unsigned short* wu_b = (unsigned short*)alloc((size_t)CHn*Kn*2);
    float*  bqs = (float*)alloc(CHn*4);
    float*  bks = (float*)alloc(CHn*4);
    unsigned short* q_s  = (unsigned short*)alloc((size_t)Bn*Hn*Tn*Kn*2);
    unsigned short* k_s  = (unsigned short*)alloc((size_t)Bn*Hn*Tn*Kn*2);
    unsigned short* v_t  = (unsigned short*)alloc((size_t)Bn*Hn*Tn*Kn*2);
    unsigned short* attn = (unsigned short*)alloc((size_t)Bn*Tn*CHn*2);

    prep_kernel<<<2048, 256, 0, stream>>>(x, wq, bq, wk, bk, wv, wu,
                                          x_pad, w2q, w2k, w2v, wu_b, bqs, bks);
    conv_v4<<<dim3(4, 8, 24), 256, 0, stream>>>(
        x_pad, w2q, w2k, w2v, bqs, bks, q_s, k_s, v_t);
    attn_kernel<<<1024, 256, 0, stream>>>(q_s, k_s, v_t, attn);
    proj_kernel<<<(Bn*Tn)/16, 256, 0, stream>>>(attn, wu_b, bu, outp);
}

// Round 19
// 113.821 us; speedup vs baseline: 1.2074x; 1.2074x over previous
//
#include <hip/hip_runtime.h>
#include <hip/hip_bf16.h>

typedef __attribute__((ext_vector_type(8))) short bf16x8;
typedef __attribute__((ext_vector_type(4))) float f32x4;
typedef __attribute__((ext_vector_type(16))) float f32x16;
typedef __attribute__((ext_vector_type(4))) unsigned int u32x4;
typedef __attribute__((ext_vector_type(2))) unsigned int u32x2;

#define Bn 8
#define Tn 2048
#define Kn 64
#define Hn 8
#define KSn 5
#define CHn 512
#define TPADn 2052  /* 4 zero rows + 2048 */

__device__ __forceinline__ unsigned short f2bf(float f) {
    unsigned int x = __builtin_bit_cast(unsigned int, f);
    unsigned int r = (x + 0x7fffu + ((x >> 16) & 1u)) >> 16;
    return (unsigned short)r;
}

__device__ __forceinline__ unsigned int cvt_pk_bf16(float lo, float hi) {
    unsigned int r;
    asm("v_cvt_pk_bf16_f32 %0, %1, %2" : "=v"(r) : "v"(lo), "v"(hi));
    return r;
}

__device__ __forceinline__ float fast_exp2(float x) {
#if __has_builtin(__builtin_amdgcn_exp2f)
    return __builtin_amdgcn_exp2f(x);
#else
    float r;
    asm("v_exp_f32 %0, %1" : "=v"(r) : "v"(x));
    return r;
#endif
}

// cross-half (lane ^ 32) merges: validated shfl_xor path (rounds 1-4,7-16).
__device__ __forceinline__ float xhalf_max(float v) {
    return fmaxf(v, __shfl_xor(v, 32));
}
__device__ __forceinline__ float xhalf_add(float v) {
    return v + __shfl_xor(v, 32);
}

// distinct-operand two-register permute (validated in P-repack since round 1)
__device__ __forceinline__ u32x2 pl32swap(unsigned int x, unsigned int y) {
#if __has_builtin(__builtin_amdgcn_permlane32_swap)
    return __builtin_amdgcn_permlane32_swap(x, y, false, false);
#else
    unsigned int xs = (unsigned int)__shfl_xor((int)x, 32);
    unsigned int ys = (unsigned int)__shfl_xor((int)y, 32);
    int hi = (threadIdx.x & 63) >> 5;
    u32x2 r;
    r[0] = hi ? ys : x;   // {x.lo | y.lo}
    r[1] = hi ? y : xs;   // {x.hi | y.hi}
    return r;
#endif
}

__device__ __forceinline__ void gload_lds16(const void* g, void* l) {
    __builtin_amdgcn_global_load_lds(
        (const __attribute__((address_space(1))) void*)g,
        (__attribute__((address_space(3))) void*)l, 16, 0, 0);
}

// ---------------- prep: conversions + padded x + weight reformat + scale folding ----
__global__ void prep_kernel(const float* __restrict__ x,
                            const float* __restrict__ wq, const float* __restrict__ bq,
                            const float* __restrict__ wk, const float* __restrict__ bk,
                            const float* __restrict__ wv,
                            const float* __restrict__ wu,
                            unsigned short* __restrict__ x_pad,
                            unsigned short* __restrict__ w2q, unsigned short* __restrict__ w2k,
                            unsigned short* __restrict__ w2v,
                            unsigned short* __restrict__ wu_b,
                            float* __restrict__ bqs, float* __restrict__ bks)
{
    // 64^-0.25 * sqrt(log2(e)): scores come out pre-multiplied by log2(e)
    const float inv_scale = 0.424660900144f;
    const int N0 = Bn*TPADn*Kn;
    const int N1 = KSn*CHn*Kn;
    const int total = N0 + 3*N1 + CHn*Kn + 2*CHn;
    for (int i = blockIdx.x*blockDim.x + threadIdx.x; i < total; i += gridDim.x*blockDim.x) {
        if (i < N0) {
            int b = i / (TPADn*Kn);
            int rem = i - b*(TPADn*Kn);
            int p = rem >> 6, ic = rem & 63;
            x_pad[i] = (p < 4) ? (unsigned short)0
                               : f2bf(x[((size_t)b*Tn + (p - 4))*Kn + ic]);
            continue;
        }
        int r = i - N0;
        if (r < 3*N1) {
            int conv = r / N1; int rr = r - conv*N1;
            int j = rr / (CHn*Kn); int rc = rr - j*(CHn*Kn);
            int c = rc >> 6; int ic = rc & 63;
            const float* w = (conv==0) ? wq : ((conv==1) ? wk : wv);
            float s = (conv==2) ? 1.0f : inv_scale;
            unsigned short* dst = (conv==0) ? w2q : ((conv==1) ? w2k : w2v);
            dst[rr] = f2bf(w[(c*Kn + ic)*KSn + j] * s);
            continue;
        }
        r -= 3*N1;
        if (r < CHn*Kn) { wu_b[r] = f2bf(wu[r]); continue; }
        r -= CHn*Kn;
        if (r < CHn) { bqs[r] = bq[r]*inv_scale; continue; }
        r -= CHn;
        bks[r] = bk[r]*inv_scale;
    }
}

// ---------------- conv v4: register weights, LDS-staged x (dbuf), 8 t-tiles/block ---
__global__ __launch_bounds__(256) void conv_v4(
    const unsigned short* __restrict__ x_pad,
    const unsigned short* __restrict__ w2q, const unsigned short* __restrict__ w2k,
    const unsigned short* __restrict__ w2v,
    const float* __restrict__ bqs, const float* __restrict__ bks,
    unsigned short* __restrict__ q_s, unsigned short* __restrict__ k_s,
    unsigned short* __restrict__ v_t)
{
    __shared__ __align__(16) unsigned short xs[2][72*64];
    __shared__ __align__(16) unsigned short ts[64*64];
    const int tg = blockIdx.x;
    const int c0 = blockIdx.y * 64;
    const int zz = blockIdx.z;
    const int conv = zz >> 3, b = zz & 7;
    const unsigned short* w2 = (conv==0) ? w2q : ((conv==1) ? w2k : w2v);
    const float* bias = (conv==0) ? bqs : ((conv==1) ? bks : nullptr);
    unsigned short* outp = (conv==0) ? q_s : ((conv==1) ? k_s : v_t);
    const int tid = threadIdx.x;
    const int wid = tid >> 6, l = tid & 63;
    const int lr = l & 15, lh = l >> 4;
    const int wt = wid & 1, wc = wid >> 1;

    bf16x8 wf[5][2][2];
    #pragma unroll
    for (int j = 0; j < 5; ++j)
        #pragma unroll
        for (int kk = 0; kk < 2; ++kk)
            #pragma unroll
            for (int n2 = 0; n2 < 2; ++n2)
                wf[j][kk][n2] = *(const bf16x8*)
                    &w2[(j*CHn + c0 + wc*32 + n2*16 + lr)*Kn + kk*32 + lh*8];
    float bv0 = bias ? bias[c0 + wc*32 + lr]      : 0.0f;
    float bv1 = bias ? bias[c0 + wc*32 + 16 + lr] : 0.0f;

    const int swz_row = l >> 3;
    const int src_inrow = ((l & 7) << 4) ^ (swz_row << 4);

    int buf = 0;
    {
        const char* base = (const char*)(x_pad + (size_t)b*TPADn*Kn);
        int p0 = tg*512;
        for (int i = wid; i < 9; i += 4) {
            const char* src = base + (size_t)(p0 + i*8 + swz_row)*128 + src_inrow;
            gload_lds16(src, (char*)&xs[0][0] + i*1024);
        }
    }
    __syncthreads();

    for (int tt = 0; tt < 8; ++tt) {
        const int t0 = (tg*8 + tt)*64;
        if (tt < 7) {
            const char* base = (const char*)(x_pad + (size_t)b*TPADn*Kn);
            int p0 = t0 + 64;
            for (int i = wid; i < 9; i += 4) {
                const char* src = base + (size_t)(p0 + i*8 + swz_row)*128 + src_inrow;
                gload_lds16(src, (char*)&xs[buf^1][0] + i*1024);
            }
        }
        const char* xb = (const char*)&xs[buf][0];
        f32x4 acc[2][2] = {};
        #pragma unroll
        for (int j = 0; j < 5; ++j)
            #pragma unroll
            for (int kk = 0; kk < 2; ++kk) {
                #pragma unroll
                for (int m = 0; m < 2; ++m) {
                    int row = wt*32 + m*16 + lr + j;
                    bf16x8 a = *(const bf16x8*)
                        (xb + row*128 + ((kk*64 + lh*16) ^ ((row & 7) << 4)));
                    acc[m][0] = __builtin_amdgcn_mfma_f32_16x16x32_bf16(a, wf[j][kk][0], acc[m][0], 0, 0, 0);
                    acc[m][1] = __builtin_amdgcn_mfma_f32_16x16x32_bf16(a, wf[j][kk][1], acc[m][1], 0, 0, 0);
                }
            }
        __syncthreads();
        #pragma unroll
        for (int m = 0; m < 2; ++m)
            #pragma unroll
            for (int n2 = 0; n2 < 2; ++n2) {
                float bv = n2 ? bv1 : bv0;
                int cl = wc*32 + n2*16 + lr;
                #pragma unroll
                for (int reg = 0; reg < 4; ++reg) {
                    int tl = wt*32 + m*16 + lh*4 + reg;
                    ts[(tl*64 + cl) ^ ((tl & 7) << 3)] = f2bf(acc[m][n2][reg] + bv);
                }
            }
        __syncthreads();
        if (conv < 2) {
            #pragma unroll
            for (int it = 0; it < 2; ++it) {
                int idx = tid + it*256;
                int tl = idx >> 3, hl = idx & 7;
                unsigned short tmp[8];
                #pragma unroll
                for (int dl = 0; dl < 8; ++dl)
                    tmp[dl] = ts[(tl*64 + hl + 8*dl) ^ ((tl & 7) << 3)];
                size_t el = ((size_t)(b*Hn + hl)*Tn + t0 + tl)*Kn + (c0 >> 3);
                *(u32x4*)&outp[el] = *(u32x4*)tmp;
            }
        } else {
            #pragma unroll
            for (int it = 0; it < 2; ++it) {
                int idx = tid + it*256;
                int tc = idx >> 6, cl2 = idx & 63;
                int hl = cl2 & 7, dl = cl2 >> 3;
                unsigned short tmp[8];
                #pragma unroll
                for (int i2 = 0; i2 < 8; ++i2)
                    tmp[i2] = ts[((tc*8 + i2)*64 + cl2) ^ (((tc*8 + i2) & 7) << 3)];
                size_t el = ((size_t)(b*Hn + hl)*Kn + (c0 >> 3) + dl)*Tn + t0 + tc*8;
                *(u32x4*)&outp[el] = *(u32x4*)tmp;
            }
        }
        buf ^= 1;
    }
}

// ---- attn v13b: r16-validated cooperative staging + setprio + longest-first --------
__global__ __launch_bounds__(256, 4) void attn_kernel(
    const unsigned short* __restrict__ q_s, const unsigned short* __restrict__ k_s,
    const unsigned short* __restrict__ v_t, unsigned short* __restrict__ attn2)
{
    __shared__ __align__(16) unsigned char lds_raw[16384];  // K dbuf 8KB + V dbuf 8KB
    const int tid = threadIdx.x;
    const int wid = tid >> 6, l = tid & 63;
    const int lq = l & 31, hi = l >> 5;
    const int bx = blockIdx.x;                   // 1024 blocks
    const int bh = (bx & 7)*8 + ((bx >> 3) & 7); // 8 heads per XCD (K+V fits L2)
    const int s4g = (bx >> 6) & 3, g = bx >> 8;
    // longest blocks first (g=0 -> j=15-s); per-CU j set {15-s, s, 8+s, 7-s} = 30
    const int j = (g == 0) ? 15 - s4g : (g == 1) ? s4g : (g == 2) ? 8 + s4g : 7 - s4g;
    const int cmax = 4*j + 3;
    const int cw = 4*j + wid;      // this wave's chunk
    const int qw = cw * 32;
    const unsigned short* qp = q_s + (size_t)bh*Tn*Kn;
    const char* kpc = (const char*)(k_s + (size_t)bh*Tn*Kn);
    const char* vpc = (const char*)(v_t + (size_t)bh*Kn*Tn);
    unsigned short* op = attn2 + (size_t)bh*Tn*Kn;
    const int qg = qw + lq;

    // block-cooperative stage: thread -> 16B of K tile + 16B of V tile
    const int krow = wid*8 + (l >> 3);
    const char* kSrc0 = kpc + krow*128 + (((l & 7) ^ (krow & 7)) << 4);
    const char* vSrc0 = vpc + (size_t)krow*8192 + ((l >> 2) & 1)*4096
                      + ((((l & 3) ^ (krow & 3))) << 4);
    const int dstOff = wid*1024;   // wave-uniform LDS dst (HW adds lane*16)
    auto stage = [&](int pp, int t) {
        gload_lds16(kSrc0 + (size_t)t*4096, lds_raw + pp*4096 + dstOff);
        gload_lds16(vSrc0 + (size_t)t*64,   lds_raw + 8192 + pp*4096 + dstOff);
    };

    bf16x8 qf[4];
    #pragma unroll
    for (int m = 0; m < 4; ++m)
        qf[m] = *(const bf16x8*)&qp[(qw + lq)*Kn + m*16 + hi*8];

    f32x16 o0 = (f32x16)(0.0f), o1 = (f32x16)(0.0f);
    float m_run = -1e30f, l_run = 0.f;   // l_run per-lane-HALF (merged at end)

    const int kReadBase = lq*128;
    const int kReadSwz  = (lq & 7) << 4;
    const int vReadBase = (lq >> 1)*128 + (lq & 1)*64;
    const int vSwz = (lq >> 1) & 3;

    stage(0, 0);
    __syncthreads();               // compiler drains vmcnt before barrier
    int p = 0;
    for (int t = 0; t <= cmax; ++t) {
        if (t < cmax) stage(p ^ 1, t + 1);   // async fill of the other buffer
        if (t <= cw) {
            const char* sK = (const char*)lds_raw + p*4096;
            const char* sV = (const char*)lds_raw + 8192 + p*4096;
            bf16x8 kbf[4], vbf[2][2];
            #pragma unroll
            for (int m = 0; m < 4; ++m)
                kbf[m] = *(const bf16x8*)(sK + kReadBase + ((m*32 + hi*16) ^ kReadSwz));
            #pragma unroll
            for (int dn = 0; dn < 2; ++dn)
                #pragma unroll
                for (int ks = 0; ks < 2; ++ks)
                    vbf[dn][ks] = *(const bf16x8*)
                        (sV + dn*2048 + vReadBase + (((ks*2 + hi) ^ vSwz) << 4));
            // QK^T (swapped): C[s][q], one q-column per lane
            const int s0 = t*32;
            f32x16 s = (f32x16)(0.0f);
            __builtin_amdgcn_s_setprio(1);   // T5: favor MFMA-issuing wave
            #pragma unroll
            for (int m = 0; m < 4; ++m)
                s = __builtin_amdgcn_mfma_f32_32x32x16_bf16(kbf[m], qf[m], s, 0, 0, 0);
            __builtin_amdgcn_s_setprio(0);
            if (t == cw) {
                #pragma unroll
                for (int r = 0; r < 16; ++r) {
                    int sg = s0 + (r & 3) + 8*(r >> 2) + 4*hi;
                    if (sg > qg) s[r] = -1e30f;
                }
            }
            float a8[8];
            #pragma unroll
            for (int r = 0; r < 8; ++r) a8[r] = fmaxf(s[r], s[r + 8]);
            float a4_0 = fmaxf(a8[0], a8[4]), a4_1 = fmaxf(a8[1], a8[5]);
            float a4_2 = fmaxf(a8[2], a8[6]), a4_3 = fmaxf(a8[3], a8[7]);
            float mt = fmaxf(fmaxf(a4_0, a4_1), fmaxf(a4_2, a4_3));
            mt = xhalf_max(mt);
            if (!__all(mt <= m_run + 8.0f)) {   // defer-max (log2 domain, THR=8)
                float mn = fmaxf(m_run, mt);
                float alpha = fast_exp2(m_run - mn);
                m_run = mn;
                l_run *= alpha;
                #pragma unroll
                for (int r = 0; r < 16; ++r) { o0[r] *= alpha; o1[r] *= alpha; }
            }
            float ps[4] = {0.f, 0.f, 0.f, 0.f};
            #pragma unroll
            for (int r = 0; r < 16; ++r) {
                float pv = fast_exp2(s[r] - m_run);
                s[r] = pv;
                ps[r & 3] += pv;
            }
            l_run += (ps[0] + ps[1]) + (ps[2] + ps[3]);
            unsigned int W[8];
            #pragma unroll
            for (int rp = 0; rp < 8; ++rp)
                W[rp] = cvt_pk_bf16(s[2*rp], s[2*rp + 1]);
            u32x4 bw[2];
            #pragma unroll
            for (int m = 0; m < 2; ++m)
                #pragma unroll
                for (int jp = 0; jp < 2; ++jp) {
                    u32x2 sw = pl32swap(W[jp + 4*m], W[jp + 4*m + 2]);
                    bw[m][jp]     = sw[0];
                    bw[m][jp + 2] = sw[1];
                }
            __builtin_amdgcn_s_setprio(1);   // T5: PV MFMA cluster
            o0 = __builtin_amdgcn_mfma_f32_32x32x16_bf16(vbf[0][0], __builtin_bit_cast(bf16x8, bw[0]), o0, 0, 0, 0);
            o0 = __builtin_amdgcn_mfma_f32_32x32x16_bf16(vbf[0][1], __builtin_bit_cast(bf16x8, bw[1]), o0, 0, 0, 0);
            o1 = __builtin_amdgcn_mfma_f32_32x32x16_bf16(vbf[1][0], __builtin_bit_cast(bf16x8, bw[0]), o1, 0, 0, 0);
            o1 = __builtin_amdgcn_mfma_f32_32x32x16_bf16(vbf[1][1], __builtin_bit_cast(bf16x8, bw[1]), o1, 0, 0, 0);
            __builtin_amdgcn_s_setprio(0);
        }
        __syncthreads();   // buf[p] reads done; buf[p^1] stage landed
        p ^= 1;
    }

    // epilogue: merge l across halves once, normalize, per-wave LDS transpose
    float l_full = xhalf_add(l_run);
    char* myLds = (char*)lds_raw + wid*4096;   // stage buffers dead after final barrier
    float inv_l = 1.0f / l_full;
    #pragma unroll
    for (int e = 0; e < 16; e += 2) {
        int dd = (e & 3) + 8*(e >> 2) + 4*hi;
        unsigned int wv0 = cvt_pk_bf16(o0[e]*inv_l, o0[e+1]*inv_l);
        *(unsigned int*)(myLds + ((lq*128 + dd*2)      ^ ((lq & 7) << 4))) = wv0;
        unsigned int wv1 = cvt_pk_bf16(o1[e]*inv_l, o1[e+1]*inv_l);
        *(unsigned int*)(myLds + ((lq*128 + 64 + dd*2) ^ ((lq & 7) << 4))) = wv1;
    }
    int q2 = l >> 1, hf = l & 1;
    #pragma unroll
    for (int o4 = 0; o4 < 4; ++o4) {
        u32x4 vr2 = *(u32x4*)(myLds + ((q2*128 + hf*64 + o4*16) ^ ((q2 & 7) << 4)));
        *(u32x4*)&op[(qw + q2)*Kn + hf*32 + o4*8] = vr2;
    }
}

// ---------------- output projection: 16 rows/block, 4-way K-split + LDS reduce ------
__global__ __launch_bounds__(256) void proj_kernel(
    const unsigned short* __restrict__ attn, const unsigned short* __restrict__ wu_b,
    const float* __restrict__ bu, float* __restrict__ outp)
{
    __shared__ float red[4*16*66];
    const int r0 = blockIdx.x * 16;
    const int tid = threadIdx.x;
    const int w = tid >> 6, l = tid & 63;
    const int lr = l & 15, lh = l >> 4;
    f32x4 acc[4] = {};
    const int r = r0 + lr;
    const int bb = r >> 11, tt = r & 2047;
    #pragma unroll
    for (int ki = 0; ki < 4; ++ki) {
        int kk = w*4 + ki;
        int ch = kk*32 + lh*8;
        int hh = ch >> 6, dd = ch & 63;
        bf16x8 a = *(const bf16x8*)&attn[(size_t)((bb*Hn + hh)*Tn + tt)*Kn + dd];
        #pragma unroll
        for (int n = 0; n < 4; ++n) {
            bf16x8 bf = *(const bf16x8*)&wu_b[(n*16 + lr)*CHn + ch];
            acc[n] = __builtin_amdgcn_mfma_f32_16x16x32_bf16(a, bf, acc[n], 0, 0, 0);
        }
    }
    #pragma unroll
    for (int n = 0; n < 4; ++n)
        #pragma unroll
        for (int reg = 0; reg < 4; ++reg)
            red[w*1056 + (lh*4 + reg)*66 + n*16 + lr] = acc[n][reg];
    __syncthreads();
    #pragma unroll
    for (int it = 0; it < 4; ++it) {
        int idx = tid + it*256;
        int rl = idx >> 6, ko = idx & 63;
        float s = red[rl*66 + ko] + red[1056 + rl*66 + ko]
                + red[2112 + rl*66 + ko] + red[3168 + rl*66 + ko] + bu[ko];
        outp[(size_t)(r0 + rl)*Kn + ko] = s;
    }
}

extern "C" void kernel_launch(void* const* d_in, const int* in_sizes, int n_in,
                              void* d_out, int out_size, void* d_ws, size_t ws_size,
                              hipStream_t stream)
{
    const float* x  = (const float*)d_in[0];
    const float* wq = (const float*)d_in[1];
    const float* bq = (const float*)d_in[2];
    const float* wk = (const float*)d_in[3];
    const float* bk = (const float*)d_in[4];
    const float* wv = (const float*)d_in[5];
    const float* wu = (const float*)d_in[6];
    const float* bu = (const float*)d_in[7];
    float* outp = (float*)d_out;

    char* ws = (char*)d_ws;
    size_t off = 0;
    auto alloc = [&](size_t bytes) {
        char* p = ws + off;
        off = (off + bytes + 255) & ~(size_t)255;
        return p;
    };
    unsigned short* x_pad = (unsigned short*)alloc((size_t)Bn*TPADn*Kn*2);
    unsigned short* w2q  = (unsigned short*)alloc((size_t)KSn*CHn*Kn*2);
    unsigned short* w2k  = (unsigned short*)alloc((size_t)KSn*CHn*Kn*2);
    unsigned short* w2v  = (unsigned short*)alloc((size_t)KSn*CHn*Kn*2);
    unsigned short* wu_b = (unsigned short*)alloc((size_t)CHn*Kn*2);
    float*  bqs = (float*)alloc(CHn*4);
    float*  bks = (float*)alloc(CHn*4);
    unsigned short* q_s  = (unsigned short*)alloc((size_t)Bn*Hn*Tn*Kn*2);
    unsigned short* k_s  = (unsigned short*)alloc((size_t)Bn*Hn*Tn*Kn*2);
    unsigned short* v_t  = (unsigned short*)alloc((size_t)Bn*Hn*Tn*Kn*2);
    unsigned short* attn = (unsigned short*)alloc((size_t)Bn*Tn*CHn*2);

    prep_kernel<<<2048, 256, 0, stream>>>(x, wq, bq, wk, bk, wv, wu,
                                          x_pad, w2q, w2k, w2v, wu_b, bqs, bks);
    conv_v4<<<dim3(4, 8, 24), 256, 0, stream>>>(
        x_pad, w2q, w2k, w2v, bqs, bks, q_s, k_s, v_t);
    attn_kernel<<<1024, 256, 0, stream>>>(q_s, k_s, v_t, attn);
    proj_kernel<<<(Bn*Tn)/16, 256, 0, stream>>>(attn, wu_b, bu, outp);
}

// Round 20
// 113.684 us; speedup vs baseline: 1.2088x; 1.0012x over previous
//
#include <hip/hip_runtime.h>
#include <hip/hip_bf16.h>

typedef __attribute__((ext_vector_type(8))) short bf16x8;
typedef __attribute__((ext_vector_type(4))) float f32x4;
typedef __attribute__((ext_vector_type(16))) float f32x16;
typedef __attribute__((ext_vector_type(4))) unsigned int u32x4;
typedef __attribute__((ext_vector_type(2))) unsigned int u32x2;

#define Bn 8
#define Tn 2048
#define Kn 64
#define Hn 8
#define KSn 5
#define CHn 512
#define TPADn 2052  /* 4 zero rows + 2048 */

__device__ __forceinline__ unsigned short f2bf(float f) {
    unsigned int x = __builtin_bit_cast(unsigned int, f);
    unsigned int r = (x + 0x7fffu + ((x >> 16) & 1u)) >> 16;
    return (unsigned short)r;
}

__device__ __forceinline__ unsigned int cvt_pk_bf16(float lo, float hi) {
    unsigned int r;
    asm("v_cvt_pk_bf16_f32 %0, %1, %2" : "=v"(r) : "v"(lo), "v"(hi));
    return r;
}

__device__ __forceinline__ float fast_exp2(float x) {
#if __has_builtin(__builtin_amdgcn_exp2f)
    return __builtin_amdgcn_exp2f(x);
#else
    float r;
    asm("v_exp_f32 %0, %1" : "=v"(r) : "v"(x));
    return r;
#endif
}

// cross-half (lane ^ 32) merges: validated shfl_xor path (rounds 1-4,7-19).
__device__ __forceinline__ float xhalf_max(float v) {
    return fmaxf(v, __shfl_xor(v, 32));
}
__device__ __forceinline__ float xhalf_add(float v) {
    return v + __shfl_xor(v, 32);
}

// distinct-operand two-register permute (validated in P-repack since round 1)
__device__ __forceinline__ u32x2 pl32swap(unsigned int x, unsigned int y) {
#if __has_builtin(__builtin_amdgcn_permlane32_swap)
    return __builtin_amdgcn_permlane32_swap(x, y, false, false);
#else
    unsigned int xs = (unsigned int)__shfl_xor((int)x, 32);
    unsigned int ys = (unsigned int)__shfl_xor((int)y, 32);
    int hi = (threadIdx.x & 63) >> 5;
    u32x2 r;
    r[0] = hi ? ys : x;   // {x.lo | y.lo}
    r[1] = hi ? y : xs;   // {x.hi | y.hi}
    return r;
#endif
}

__device__ __forceinline__ void gload_lds16(const void* g, void* l) {
    __builtin_amdgcn_global_load_lds(
        (const __attribute__((address_space(1))) void*)g,
        (__attribute__((address_space(3))) void*)l, 16, 0, 0);
}

// ---------------- prep: conversions + padded x + weight reformat + scale folding ----
__global__ void prep_kernel(const float* __restrict__ x,
                            const float* __restrict__ wq, const float* __restrict__ bq,
                            const float* __restrict__ wk, const float* __restrict__ bk,
                            const float* __restrict__ wv,
                            const float* __restrict__ wu,
                            unsigned short* __restrict__ x_pad,
                            unsigned short* __restrict__ w2q, unsigned short* __restrict__ w2k,
                            unsigned short* __restrict__ w2v,
                            unsigned short* __restrict__ wu_b,
                            float* __restrict__ bqs, float* __restrict__ bks)
{
    // 64^-0.25 * sqrt(log2(e)): scores come out pre-multiplied by log2(e)
    const float inv_scale = 0.424660900144f;
    const int N0 = Bn*TPADn*Kn;
    const int N1 = KSn*CHn*Kn;
    const int total = N0 + 3*N1 + CHn*Kn + 2*CHn;
    for (int i = blockIdx.x*blockDim.x + threadIdx.x; i < total; i += gridDim.x*blockDim.x) {
        if (i < N0) {
            int b = i / (TPADn*Kn);
            int rem = i - b*(TPADn*Kn);
            int p = rem >> 6, ic = rem & 63;
            x_pad[i] = (p < 4) ? (unsigned short)0
                               : f2bf(x[((size_t)b*Tn + (p - 4))*Kn + ic]);
            continue;
        }
        int r = i - N0;
        if (r < 3*N1) {
            int conv = r / N1; int rr = r - conv*N1;
            int j = rr / (CHn*Kn); int rc = rr - j*(CHn*Kn);
            int c = rc >> 6; int ic = rc & 63;
            const float* w = (conv==0) ? wq : ((conv==1) ? wk : wv);
            float s = (conv==2) ? 1.0f : inv_scale;
            unsigned short* dst = (conv==0) ? w2q : ((conv==1) ? w2k : w2v);
            dst[rr] = f2bf(w[(c*Kn + ic)*KSn + j] * s);
            continue;
        }
        r -= 3*N1;
        if (r < CHn*Kn) { wu_b[r] = f2bf(wu[r]); continue; }
        r -= CHn*Kn;
        if (r < CHn) { bqs[r] = bq[r]*inv_scale; continue; }
        r -= CHn;
        bks[r] = bk[r]*inv_scale;
    }
}

// ---- conv v5: register weights, LDS-staged x (dbuf), 4 t-tiles/block (6 blk/CU) ----
__global__ __launch_bounds__(256) void conv_v4(
    const unsigned short* __restrict__ x_pad,
    const unsigned short* __restrict__ w2q, const unsigned short* __restrict__ w2k,
    const unsigned short* __restrict__ w2v,
    const float* __restrict__ bqs, const float* __restrict__ bks,
    unsigned short* __restrict__ q_s, unsigned short* __restrict__ k_s,
    unsigned short* __restrict__ v_t)
{
    __shared__ __align__(16) unsigned short xs[2][72*64];
    __shared__ __align__(16) unsigned short ts[64*64];
    const int tg = blockIdx.x;        // 0..7 (group of 4 t-tiles)
    const int c0 = blockIdx.y * 64;
    const int zz = blockIdx.z;
    const int conv = zz >> 3, b = zz & 7;
    const unsigned short* w2 = (conv==0) ? w2q : ((conv==1) ? w2k : w2v);
    const float* bias = (conv==0) ? bqs : ((conv==1) ? bks : nullptr);
    unsigned short* outp = (conv==0) ? q_s : ((conv==1) ? k_s : v_t);
    const int tid = threadIdx.x;
    const int wid = tid >> 6, l = tid & 63;
    const int lr = l & 15, lh = l >> 4;
    const int wt = wid & 1, wc = wid >> 1;

    bf16x8 wf[5][2][2];
    #pragma unroll
    for (int j = 0; j < 5; ++j)
        #pragma unroll
        for (int kk = 0; kk < 2; ++kk)
            #pragma unroll
            for (int n2 = 0; n2 < 2; ++n2)
                wf[j][kk][n2] = *(const bf16x8*)
                    &w2[(j*CHn + c0 + wc*32 + n2*16 + lr)*Kn + kk*32 + lh*8];
    float bv0 = bias ? bias[c0 + wc*32 + lr]      : 0.0f;
    float bv1 = bias ? bias[c0 + wc*32 + 16 + lr] : 0.0f;

    const int swz_row = l >> 3;
    const int src_inrow = ((l & 7) << 4) ^ (swz_row << 4);

    int buf = 0;
    {
        const char* base = (const char*)(x_pad + (size_t)b*TPADn*Kn);
        int p0 = tg*256;
        for (int i = wid; i < 9; i += 4) {
            const char* src = base + (size_t)(p0 + i*8 + swz_row)*128 + src_inrow;
            gload_lds16(src, (char*)&xs[0][0] + i*1024);
        }
    }
    __syncthreads();

    for (int tt = 0; tt < 4; ++tt) {
        const int t0 = (tg*4 + tt)*64;
        if (tt < 3) {
            const char* base = (const char*)(x_pad + (size_t)b*TPADn*Kn);
            int p0 = t0 + 64;
            for (int i = wid; i < 9; i += 4) {
                const char* src = base + (size_t)(p0 + i*8 + swz_row)*128 + src_inrow;
                gload_lds16(src, (char*)&xs[buf^1][0] + i*1024);
            }
        }
        const char* xb = (const char*)&xs[buf][0];
        f32x4 acc[2][2] = {};
        #pragma unroll
        for (int j = 0; j < 5; ++j)
            #pragma unroll
            for (int kk = 0; kk < 2; ++kk) {
                #pragma unroll
                for (int m = 0; m < 2; ++m) {
                    int row = wt*32 + m*16 + lr + j;
                    bf16x8 a = *(const bf16x8*)
                        (xb + row*128 + ((kk*64 + lh*16) ^ ((row & 7) << 4)));
                    acc[m][0] = __builtin_amdgcn_mfma_f32_16x16x32_bf16(a, wf[j][kk][0], acc[m][0], 0, 0, 0);
                    acc[m][1] = __builtin_amdgcn_mfma_f32_16x16x32_bf16(a, wf[j][kk][1], acc[m][1], 0, 0, 0);
                }
            }
        __syncthreads();
        #pragma unroll
        for (int m = 0; m < 2; ++m)
            #pragma unroll
            for (int n2 = 0; n2 < 2; ++n2) {
                float bv = n2 ? bv1 : bv0;
                int cl = wc*32 + n2*16 + lr;
                #pragma unroll
                for (int reg = 0; reg < 4; ++reg) {
                    int tl = wt*32 + m*16 + lh*4 + reg;
                    ts[(tl*64 + cl) ^ ((tl & 7) << 3)] = f2bf(acc[m][n2][reg] + bv);
                }
            }
        __syncthreads();
        if (conv < 2) {
            #pragma unroll
            for (int it = 0; it < 2; ++it) {
                int idx = tid + it*256;
                int tl = idx >> 3, hl = idx & 7;
                unsigned short tmp[8];
                #pragma unroll
                for (int dl = 0; dl < 8; ++dl)
                    tmp[dl] = ts[(tl*64 + hl + 8*dl) ^ ((tl & 7) << 3)];
                size_t el = ((size_t)(b*Hn + hl)*Tn + t0 + tl)*Kn + (c0 >> 3);
                *(u32x4*)&outp[el] = *(u32x4*)tmp;
            }
        } else {
            #pragma unroll
            for (int it = 0; it < 2; ++it) {
                int idx = tid + it*256;
                int tc = idx >> 6, cl2 = idx & 63;
                int hl = cl2 & 7, dl = cl2 >> 3;
                unsigned short tmp[8];
                #pragma unroll
                for (int i2 = 0; i2 < 8; ++i2)
                    tmp[i2] = ts[((tc*8 + i2)*64 + cl2) ^ (((tc*8 + i2) & 7) << 3)];
                size_t el = ((size_t)(b*Hn + hl)*Kn + (c0 >> 3) + dl)*Tn + t0 + tc*8;
                *(u32x4*)&outp[el] = *(u32x4*)tmp;
            }
        }
        buf ^= 1;
    }
}

// ---- attn v13b: r16-validated cooperative staging + setprio + longest-first --------
__global__ __launch_bounds__(256, 4) void attn_kernel(
    const unsigned short* __restrict__ q_s, const unsigned short* __restrict__ k_s,
    const unsigned short* __restrict__ v_t, unsigned short* __restrict__ attn2)
{
    __shared__ __align__(16) unsigned char lds_raw[16384];  // K dbuf 8KB + V dbuf 8KB
    const int tid = threadIdx.x;
    const int wid = tid >> 6, l = tid & 63;
    const int lq = l & 31, hi = l >> 5;
    const int bx = blockIdx.x;                   // 1024 blocks
    const int bh = (bx & 7)*8 + ((bx >> 3) & 7); // 8 heads per XCD (K+V fits L2)
    const int s4g = (bx >> 6) & 3, g = bx >> 8;
    // longest blocks first (g=0 -> j=15-s); per-CU j set {15-s, s, 8+s, 7-s} = 30
    const int j = (g == 0) ? 15 - s4g : (g == 1) ? s4g : (g == 2) ? 8 + s4g : 7 - s4g;
    const int cmax = 4*j + 3;
    const int cw = 4*j + wid;      // this wave's chunk
    const int qw = cw * 32;
    const unsigned short* qp = q_s + (size_t)bh*Tn*Kn;
    const char* kpc = (const char*)(k_s + (size_t)bh*Tn*Kn);
    const char* vpc = (const char*)(v_t + (size_t)bh*Kn*Tn);
    unsigned short* op = attn2 + (size_t)bh*Tn*Kn;
    const int qg = qw + lq;

    // block-cooperative stage: thread -> 16B of K tile + 16B of V tile
    const int krow = wid*8 + (l >> 3);
    const char* kSrc0 = kpc + krow*128 + (((l & 7) ^ (krow & 7)) << 4);
    const char* vSrc0 = vpc + (size_t)krow*8192 + ((l >> 2) & 1)*4096
                      + ((((l & 3) ^ (krow & 3))) << 4);
    const int dstOff = wid*1024;   // wave-uniform LDS dst (HW adds lane*16)
    auto stage = [&](int pp, int t) {
        gload_lds16(kSrc0 + (size_t)t*4096, lds_raw + pp*4096 + dstOff);
        gload_lds16(vSrc0 + (size_t)t*64,   lds_raw + 8192 + pp*4096 + dstOff);
    };

    bf16x8 qf[4];
    #pragma unroll
    for (int m = 0; m < 4; ++m)
        qf[m] = *(const bf16x8*)&qp[(qw + lq)*Kn + m*16 + hi*8];

    f32x16 o0 = (f32x16)(0.0f), o1 = (f32x16)(0.0f);
    float m_run = -1e30f, l_run = 0.f;   // l_run per-lane-HALF (merged at end)

    const int kReadBase = lq*128;
    const int kReadSwz  = (lq & 7) << 4;
    const int vReadBase = (lq >> 1)*128 + (lq & 1)*64;
    const int vSwz = (lq >> 1) & 3;

    stage(0, 0);
    __syncthreads();               // compiler drains vmcnt before barrier
    int p = 0;
    for (int t = 0; t <= cmax; ++t) {
        if (t < cmax) stage(p ^ 1, t + 1);   // async fill of the other buffer
        if (t <= cw) {
            const char* sK = (const char*)lds_raw + p*4096;
            const char* sV = (const char*)lds_raw + 8192 + p*4096;
            bf16x8 kbf[4], vbf[2][2];
            #pragma unroll
            for (int m = 0; m < 4; ++m)
                kbf[m] = *(const bf16x8*)(sK + kReadBase + ((m*32 + hi*16) ^ kReadSwz));
            #pragma unroll
            for (int dn = 0; dn < 2; ++dn)
                #pragma unroll
                for (int ks = 0; ks < 2; ++ks)
                    vbf[dn][ks] = *(const bf16x8*)
                        (sV + dn*2048 + vReadBase + (((ks*2 + hi) ^ vSwz) << 4));
            // QK^T (swapped): C[s][q], one q-column per lane
            const int s0 = t*32;
            f32x16 s = (f32x16)(0.0f);
            __builtin_amdgcn_s_setprio(1);
            #pragma unroll
            for (int m = 0; m < 4; ++m)
                s = __builtin_amdgcn_mfma_f32_32x32x16_bf16(kbf[m], qf[m], s, 0, 0, 0);
            __builtin_amdgcn_s_setprio(0);
            if (t == cw) {
                #pragma unroll
                for (int r = 0; r < 16; ++r) {
                    int sg = s0 + (r & 3) + 8*(r >> 2) + 4*hi;
                    if (sg > qg) s[r] = -1e30f;
                }
            }
            float a8[8];
            #pragma unroll
            for (int r = 0; r < 8; ++r) a8[r] = fmaxf(s[r], s[r + 8]);
            float a4_0 = fmaxf(a8[0], a8[4]), a4_1 = fmaxf(a8[1], a8[5]);
            float a4_2 = fmaxf(a8[2], a8[6]), a4_3 = fmaxf(a8[3], a8[7]);
            float mt = fmaxf(fmaxf(a4_0, a4_1), fmaxf(a4_2, a4_3));
            mt = xhalf_max(mt);
            if (!__all(mt <= m_run + 8.0f)) {   // defer-max (log2 domain, THR=8)
                float mn = fmaxf(m_run, mt);
                float alpha = fast_exp2(m_run - mn);
                m_run = mn;
                l_run *= alpha;
                #pragma unroll
                for (int r = 0; r < 16; ++r) { o0[r] *= alpha; o1[r] *= alpha; }
            }
            float ps[4] = {0.f, 0.f, 0.f, 0.f};
            #pragma unroll
            for (int r = 0; r < 16; ++r) {
                float pv = fast_exp2(s[r] - m_run);
                s[r] = pv;
                ps[r & 3] += pv;
            }
            l_run += (ps[0] + ps[1]) + (ps[2] + ps[3]);
            unsigned int W[8];
            #pragma unroll
            for (int rp = 0; rp < 8; ++rp)
                W[rp] = cvt_pk_bf16(s[2*rp], s[2*rp + 1]);
            u32x4 bw[2];
            #pragma unroll
            for (int m = 0; m < 2; ++m)
                #pragma unroll
                for (int jp = 0; jp < 2; ++jp) {
                    u32x2 sw = pl32swap(W[jp + 4*m], W[jp + 4*m + 2]);
                    bw[m][jp]     = sw[0];
                    bw[m][jp + 2] = sw[1];
                }
            __builtin_amdgcn_s_setprio(1);
            o0 = __builtin_amdgcn_mfma_f32_32x32x16_bf16(vbf[0][0], __builtin_bit_cast(bf16x8, bw[0]), o0, 0, 0, 0);
            o0 = __builtin_amdgcn_mfma_f32_32x32x16_bf16(vbf[0][1], __builtin_bit_cast(bf16x8, bw[1]), o0, 0, 0, 0);
            o1 = __builtin_amdgcn_mfma_f32_32x32x16_bf16(vbf[1][0], __builtin_bit_cast(bf16x8, bw[0]), o1, 0, 0, 0);
            o1 = __builtin_amdgcn_mfma_f32_32x32x16_bf16(vbf[1][1], __builtin_bit_cast(bf16x8, bw[1]), o1, 0, 0, 0);
            __builtin_amdgcn_s_setprio(0);
        }
        __syncthreads();   // buf[p] reads done; buf[p^1] stage landed
        p ^= 1;
    }

    // epilogue: merge l across halves once, normalize, per-wave LDS transpose
    float l_full = xhalf_add(l_run);
    char* myLds = (char*)lds_raw + wid*4096;   // stage buffers dead after final barrier
    float inv_l = 1.0f / l_full;
    #pragma unroll
    for (int e = 0; e < 16; e += 2) {
        int dd = (e & 3) + 8*(e >> 2) + 4*hi;
        unsigned int wv0 = cvt_pk_bf16(o0[e]*inv_l, o0[e+1]*inv_l);
        *(unsigned int*)(myLds + ((lq*128 + dd*2)      ^ ((lq & 7) << 4))) = wv0;
        unsigned int wv1 = cvt_pk_bf16(o1[e]*inv_l, o1[e+1]*inv_l);
        *(unsigned int*)(myLds + ((lq*128 + 64 + dd*2) ^ ((lq & 7) << 4))) = wv1;
    }
    int q2 = l >> 1, hf = l & 1;
    #pragma unroll
    for (int o4 = 0; o4 < 4; ++o4) {
        u32x4 vr2 = *(u32x4*)(myLds + ((q2*128 + hf*64 + o4*16) ^ ((q2 & 7) << 4)));
        *(u32x4*)&op[(qw + q2)*Kn + hf*32 + o4*8] = vr2;
    }
}

// ---------------- output projection: 16 rows/block, 4-way K-split + LDS reduce ------
__global__ __launch_bounds__(256) void proj_kernel(
    const unsigned short* __restrict__ attn, const unsigned short* __restrict__ wu_b,
    const float* __restrict__ bu, float* __restrict__ outp)
{
    __shared__ float red[4*16*66];
    const int r0 = blockIdx.x * 16;
    const int tid = threadIdx.x;
    const int w = tid >> 6, l = tid & 63;
    const int lr = l & 15, lh = l >> 4;
    f32x4 acc[4] = {};
    const int r = r0 + lr;
    const int bb = r >> 11, tt = r & 2047;
    #pragma unroll
    for (int ki = 0; ki < 4; ++ki) {
        int kk = w*4 + ki;
        int ch = kk*32 + lh*8;
        int hh = ch >> 6, dd = ch & 63;
        bf16x8 a = *(const bf16x8*)&attn[(size_t)((bb*Hn + hh)*Tn + tt)*Kn + dd];
        #pragma unroll
        for (int n = 0; n < 4; ++n) {
            bf16x8 bf = *(const bf16x8*)&wu_b[(n*16 + lr)*CHn + ch];
            acc[n] = __builtin_amdgcn_mfma_f32_16x16x32_bf16(a, bf, acc[n], 0, 0, 0);
        }
    }
    #pragma unroll
    for (int n = 0; n < 4; ++n)
        #pragma unroll
        for (int reg = 0; reg < 4; ++reg)
            red[w*1056 + (lh*4 + reg)*66 + n*16 + lr] = acc[n][reg];
    __syncthreads();
    #pragma unroll
    for (int it = 0; it < 4; ++it) {
        int idx = tid + it*256;
        int rl = idx >> 6, ko = idx & 63;
        float s = red[rl*66 + ko] + red[1056 + rl*66 + ko]
                + red[2112 + rl*66 + ko] + red[3168 + rl*66 + ko] + bu[ko];
        outp[(size_t)(r0 + rl)*Kn + ko] = s;
    }
}

extern "C" void kernel_launch(void* const* d_in, const int* in_sizes, int n_in,
                              void* d_out, int out_size, void* d_ws, size_t ws_size,
                              hipStream_t stream)
{
    const float* x  = (const float*)d_in[0];
    const float* wq = (const float*)d_in[1];
    const float* bq = (const float*)d_in[2];
    const float* wk = (const float*)d_in[3];
    const float* bk = (const float*)d_in[4];
    const float* wv = (const float*)d_in[5];
    const float* wu = (const float*)d_in[6];
    const float* bu = (const float*)d_in[7];
    float* outp = (float*)d_out;

    char* ws = (char*)d_ws;
    size_t off = 0;
    auto alloc = [&](size_t bytes) {
        char* p = ws + off;
        off = (off + bytes + 255) & ~(size_t)255;
        return p;
    };
    unsigned short* x_pad = (unsigned short*)alloc((size_t)Bn*TPADn*Kn*2);
    unsigned short* w2q  = (unsigned short*)alloc((size_t)KSn*CHn*Kn*2);
    unsigned short* w2k  = (unsigned short*)alloc((size_t)KSn*CHn*Kn*2);
    unsigned short* w2v  = (unsigned short*)alloc((size_t)KSn*CHn*Kn*2);
    unsigned short* wu_b = (unsigned short*)alloc((size_t)CHn*Kn*2);
    float*  bqs = (float*)alloc(CHn*4);
    float*  bks = (float*)alloc(CHn*4);
    unsigned short* q_s  = (unsigned short*)alloc((size_t)Bn*Hn*Tn*Kn*2);
    unsigned short* k_s  = (unsigned short*)alloc((size_t)Bn*Hn*Tn*Kn*2);
    unsigned short* v_t  = (unsigned short*)alloc((size_t)Bn*Hn*Tn*Kn*2);
    unsigned short* attn = (unsigned short*)alloc((size_t)Bn*Tn*CHn*2);

    prep_kernel<<<2048, 256, 0, stream>>>(x, wq, bq, wk, bk, wv, wu,
                                          x_pad, w2q, w2k, w2v, wu_b, bqs, bks);
    conv_v4<<<dim3(8, 8, 24), 256, 0, stream>>>(
        x_pad, w2q, w2k, w2v, bqs, bks, q_s, k_s, v_t);
    attn_kernel<<<1024, 256, 0, stream>>>(q_s, k_s, v_t, attn);
    proj_kernel<<<(Bn*Tn)/16, 256, 0, stream>>>(attn, wu_b, bu, outp);
}